// Round 9
// baseline (75.332 us; speedup 1.0000x reference)
//
#include <hip/hip_runtime.h>

#define NB 16     // batch
#define CD 128    // channels
#define HW 4096   // spatial L
#define DD 512    // projected dim
#define KC 64     // clusters

typedef __attribute__((ext_vector_type(8))) short bfrag;           // 8 bf16 (4 VGPR)
typedef __attribute__((ext_vector_type(4))) float facc;            // MFMA acc

__device__ __forceinline__ unsigned short f2bf(float f) {
  union { float f; unsigned u; } v; v.f = f;
  unsigned r = v.u + 0x7fffu + ((v.u >> 16) & 1u);   // RNE
  return (unsigned short)(r >> 16);
}
__device__ __forceinline__ float bf2f(unsigned short h) {
  union { unsigned u; float f; } v; v.u = ((unsigned)h) << 16; return v.f;
}
// packed f32x2 -> bf16x2 (RNE), low16 = lo
__device__ __forceinline__ unsigned f2bf2(float lo, float hi) {
  unsigned r;
  asm("v_cvt_pk_bf16_f32 %0, %1, %2" : "=v"(r) : "v"(lo), "v"(hi));
  return r;
}
// async global->LDS: HW writes lds + lane*16; global src carries the per-lane offset
__device__ __forceinline__ void gll16(const void* g, void* l) {
  __builtin_amdgcn_global_load_lds(
      (__attribute__((address_space(1))) void*)(uintptr_t)g,
      (__attribute__((address_space(3))) void*)(uintptr_t)l, 16, 0, 0);
}

// ---------- prep: build pre-swizzled LDS images ----------
// Wsw: 8 chunks x [64d x 256B], byte = dch*16384 + d*256 + ((c*2)^((d&7)<<4))
// Cbsw (normalized): 8 chunks x [64k x 128B], byte = dch*8192 + k*128 + ((dl*2)^((k&7)<<4))
__global__ __launch_bounds__(256) void k_prep(const float* __restrict__ conv_w,
                                              const float* __restrict__ centroids,
                                              unsigned short* __restrict__ Wsw,
                                              unsigned short* __restrict__ Cbsw) {
  int b = blockIdx.x, t = threadIdx.x;
  if (b < KC) {
    const float* row = centroids + (size_t)b * DD;
    float v0 = row[t], v1 = row[t + 256];
    float ss = v0 * v0 + v1 * v1;
    #pragma unroll
    for (int off = 32; off; off >>= 1) ss += __shfl_xor(ss, off);
    __shared__ float red[4];
    if ((t & 63) == 0) red[t >> 6] = ss;
    __syncthreads();
    float tot = red[0] + red[1] + red[2] + red[3];
    float inv = 1.0f / fmaxf(sqrtf(tot), 1e-12f);
    int dg0 = t, dg1 = t + 256;
    *(unsigned short*)((char*)Cbsw + (dg0 >> 6) * 8192 + b * 128 +
                       (((dg0 & 63) * 2) ^ ((b & 7) << 4))) = f2bf(v0 * inv);
    *(unsigned short*)((char*)Cbsw + (dg1 >> 6) * 8192 + b * 128 +
                       (((dg1 & 63) * 2) ^ ((b & 7) << 4))) = f2bf(v1 * inv);
  } else {
    int i = (b - KC) * 2048 + t * 8;            // 32 blocks cover 65536 elems
    const float4* src = (const float4*)(conv_w + i);
    float4 a = src[0], c4 = src[1];
    int dg = i >> 7, c0 = i & 127;
    int dch = dg >> 6, d = dg & 63;
    uint4 w;
    w.x = f2bf2(a.x, a.y);  w.y = f2bf2(a.z, a.w);
    w.z = f2bf2(c4.x, c4.y); w.w = f2bf2(c4.z, c4.w);
    *(uint4*)((char*)Wsw + dch * 16384 + d * 256 + ((c0 * 2) ^ ((d & 7) << 4))) = w;
  }
}

// ---------- fused xnorm + projection + logits/exp ----------
// T3-lite: double-buffered gll16 staging, 2 barriers/dch, 12-MFMA clusters.
// LDS: xt/Ws0 [0,16K) | Ws1 [16K,32K) | psum/Xn [32K,48K) | Cb0/etile [48K,56K)
//      Cb1 [56K,64K) | fbuf [64K,72K) | ps [72K,73K)
__global__ __launch_bounds__(512, 4) void k_xproj(const float* __restrict__ x,
                                                  const unsigned short* __restrict__ Wsw,
                                                  const unsigned short* __restrict__ Cbsw,
                                                  const float* __restrict__ conv_b,
                                                  unsigned short* __restrict__ fT,
                                                  unsigned short* __restrict__ eg,
                                                  float* __restrict__ psums) {
  __shared__ __align__(16) char smem[74752];
  char* xt    = smem;                     // byte = c*128 + ((l*2) ^ ((c&15)<<3))
  char* WsB[2] = { smem, smem + 16384 };
  float* psum = (float*)(smem + 32768);   // [8][64]
  char* Xn    = smem + 32768;             // byte = l*256 + ((c*2) ^ ((l&7)<<4))
  char* CbB[2] = { smem + 49152, smem + 57344 };
  char* etile = smem + 49152;             // byte = k*128 + ((l*2) ^ ((k&7)<<4))
  char* fbuf  = smem + 65536;             // byte = l*128 + ((d*2) ^ ((l&7)<<4))
  float* ps   = (float*)(smem + 73728);   // [64][4]
  int n = blockIdx.y, l0 = blockIdx.x * 64;
  int t = threadIdx.x, lane = t & 63, wid = t >> 6;

  // P1: x (c, l0..+64) fp32 -> bf16 -> xt swizzled
  {
    int c = t >> 2;
    const float4* xrow = (const float4*)(x + ((size_t)n * CD + c) * HW + l0);
    int sw = (c & 15) << 3;
    #pragma unroll
    for (int j = 0; j < 4; j++) {
      int fq = (t & 3) + 4 * j;
      float4 v = xrow[fq];
      uint2 w;
      w.x = f2bf2(v.x, v.y); w.y = f2bf2(v.z, v.w);
      *(uint2*)(xt + c * 128 + ((fq * 8) ^ sw)) = w;
    }
  }
  __syncthreads();
  // P2: per-l sum of squares, 8 c-groups
  {
    int l = t & 63, g = t >> 6;
    float ss = 0.f;
    #pragma unroll
    for (int i = 0; i < 16; i++) {
      int c = g * 16 + i;
      float v = bf2f(*(const unsigned short*)(xt + c * 128 + ((l * 2) ^ ((c & 15) << 3))));
      ss += v * v;
    }
    psum[g * 64 + l] = ss;
  }
  __syncthreads();
  // P3: inv per l; transpose-normalize xt -> Xn
  {
    int l = t & 63, g = t >> 6;
    float tot = 0.f;
    #pragma unroll
    for (int gg = 0; gg < 8; gg++) tot += psum[gg * 64 + l];
    float inv = 1.0f / fmaxf(sqrtf(tot), 1e-12f);
    __syncthreads();                            // psum reads done before Xn writes
    #pragma unroll
    for (int h = 0; h < 2; h++) {
      int c0 = g * 16 + h * 8;
      float a0 = bf2f(*(const unsigned short*)(xt + (c0+0) * 128 + ((l*2) ^ (((c0+0)&15)<<3)))) * inv;
      float a1 = bf2f(*(const unsigned short*)(xt + (c0+1) * 128 + ((l*2) ^ (((c0+1)&15)<<3)))) * inv;
      float a2 = bf2f(*(const unsigned short*)(xt + (c0+2) * 128 + ((l*2) ^ (((c0+2)&15)<<3)))) * inv;
      float a3 = bf2f(*(const unsigned short*)(xt + (c0+3) * 128 + ((l*2) ^ (((c0+3)&15)<<3)))) * inv;
      float a4 = bf2f(*(const unsigned short*)(xt + (c0+4) * 128 + ((l*2) ^ (((c0+4)&15)<<3)))) * inv;
      float a5 = bf2f(*(const unsigned short*)(xt + (c0+5) * 128 + ((l*2) ^ (((c0+5)&15)<<3)))) * inv;
      float a6 = bf2f(*(const unsigned short*)(xt + (c0+6) * 128 + ((l*2) ^ (((c0+6)&15)<<3)))) * inv;
      float a7 = bf2f(*(const unsigned short*)(xt + (c0+7) * 128 + ((l*2) ^ (((c0+7)&15)<<3)))) * inv;
      uint4 w;
      w.x = f2bf2(a0, a1); w.y = f2bf2(a2, a3);
      w.z = f2bf2(a4, a5); w.w = f2bf2(a6, a7);
      *(uint4*)(Xn + l * 256 + ((c0 * 2) ^ ((l & 7) << 4))) = w;
    }
  }
  __syncthreads();                              // xt reads done -> Ws0 staging may begin

  // prologue: stage dch 0
  {
    const char* wsrc = (const char*)Wsw;
    #pragma unroll
    for (int q = 0; q < 2; q++)
      gll16(wsrc + (q * 8 + wid) * 1024 + lane * 16, WsB[0] + (q * 8 + wid) * 1024);
    gll16((const char*)Cbsw + wid * 1024 + lane * 16, CbB[0] + wid * 1024);
  }
  __syncthreads();                              // stage(0) complete

  // P4: 8 d-chunks of 64.  f waves 4lx2d; e waves 2kx4l.
  int wr = wid >> 1, wc = wid & 1;
  int er = wid >> 2, ec = wid & 3;
  int r0 = (lane >> 4) << 2, cl = lane & 15;
  facc zero = {0.f, 0.f, 0.f, 0.f};
  facc e_acc[2];
  e_acc[0] = zero; e_acc[1] = zero;

  #pragma unroll
  for (int dch = 0; dch < 8; dch++) {
    const char* Ws  = WsB[dch & 1];
    const char* Cbs = CbB[dch & 1];
    // f-MFMA: 64l x 64d = Xn(64l x 128c) * Ws(64d x 128c)^T
    facc acc[2];
    acc[0] = zero; acc[1] = zero;
    #pragma unroll
    for (int kk = 0; kk < 128; kk += 32) {
      int c0 = kk + ((lane >> 4) << 3);
      int row = wr * 16 + (lane & 15);
      bfrag af = *(const bfrag*)(Xn + row * 256 + ((c0 * 2) ^ ((row & 7) << 4)));
      #pragma unroll
      for (int j = 0; j < 2; j++) {
        int drow = wc * 32 + j * 16 + (lane & 15);
        bfrag bf = *(const bfrag*)(Ws + drow * 256 + ((c0 * 2) ^ ((drow & 7) << 4)));
        acc[j] = __builtin_amdgcn_mfma_f32_16x16x32_bf16(af, bf, acc[j], 0, 0, 0);
      }
    }
    __syncthreads();                            // B1: f reads of Ws done, prev fbuf/Cbs reads done
    // issue next stage (async, lands by B2)
    if (dch < 7) {
      const char* wsrc = (const char*)Wsw + (dch + 1) * 16384;
      char* wdst = WsB[(dch + 1) & 1];
      #pragma unroll
      for (int q = 0; q < 2; q++)
        gll16(wsrc + (q * 8 + wid) * 1024 + lane * 16, wdst + (q * 8 + wid) * 1024);
      gll16((const char*)Cbsw + (dch + 1) * 8192 + wid * 1024 + lane * 16,
            CbB[(dch + 1) & 1] + wid * 1024);
    }
    // epilogue: +bias -> fbuf (bf16, swizzled)
    {
      int lrow0 = wr * 16 + r0;
      #pragma unroll
      for (int j = 0; j < 2; j++) {
        int dloc = wc * 32 + j * 16 + cl;
        float bv = conv_b[dch * 64 + dloc];
        #pragma unroll
        for (int q = 0; q < 4; q++) {
          int lrow = lrow0 + q;
          *(unsigned short*)(fbuf + lrow * 128 + ((dloc * 2) ^ ((lrow & 7) << 4))) =
              f2bf(acc[j][q] + bv);
        }
      }
    }
    __syncthreads();                            // B2: fbuf visible, stage(dch+1) complete
    // coalesced fT dump (stores drain by next B1, overlapped with both MFMA clusters)
    {
      int l = t >> 3, cj = t & 7;
      bfrag v = *(const bfrag*)(fbuf + l * 128 + ((cj * 16) ^ ((l & 7) << 4)));
      *(bfrag*)(fT + ((size_t)n * HW + l0 + l) * DD + dch * 64 + cj * 8) = v;
    }
    // e-MFMA: e_acc += Cbs(64k x 64d) * fbuf(64l x 64d)^T  [flows into next f-MFMA]
    #pragma unroll
    for (int kk = 0; kk < 64; kk += 32) {
      int d0 = kk + ((lane >> 4) << 3);
      int l2 = ec * 16 + (lane & 15);
      bfrag fb = *(const bfrag*)(fbuf + l2 * 128 + ((d0 * 2) ^ ((l2 & 7) << 4)));
      #pragma unroll
      for (int m2 = 0; m2 < 2; m2++) {
        int k2 = er * 32 + m2 * 16 + (lane & 15);
        bfrag ca = *(const bfrag*)(Cbs + k2 * 128 + ((d0 * 2) ^ ((k2 & 7) << 4)));
        e_acc[m2] = __builtin_amdgcn_mfma_f32_16x16x32_bf16(ca, fb, e_acc[m2], 0, 0, 0);
      }
    }
  }

  __syncthreads();                              // Cb0/fbuf reads done -> etile/ps
  // P5: exp -> etile (pre-swizzled e-image) + rowsum partials
  {
    int l2 = ec * 16 + cl;
    #pragma unroll
    for (int m2 = 0; m2 < 2; m2++) {
      #pragma unroll
      for (int q = 0; q < 4; q++) {
        int k2 = er * 32 + m2 * 16 + r0 + q;
        float ev = __expf(e_acc[m2][q]);
        *(unsigned short*)(etile + k2 * 128 + ((l2 * 2) ^ ((k2 & 7) << 4))) = f2bf(ev);
        float v = ev;
        v += __shfl_xor(v, 1); v += __shfl_xor(v, 2);
        v += __shfl_xor(v, 4); v += __shfl_xor(v, 8);
        if (cl == 0) ps[k2 * 4 + ec] = v;
      }
    }
  }
  __syncthreads();
  // raw image dump (8K, coalesced)
  {
    uint4 v = *(const uint4*)(etile + t * 16);
    *(uint4*)((char*)eg + ((size_t)n * 64 + blockIdx.x) * 8192 + t * 16) = v;
  }
  if (t < 64)
    psums[((size_t)n * 64 + blockIdx.x) * 64 + t] =
        ps[t * 4] + ps[t * 4 + 1] + ps[t * 4 + 2] + ps[t * 4 + 3];
}

// ---------- rinv[n,k] = 1 / sum_tiles psums ----------
__global__ __launch_bounds__(256) void k_rinv(const float* __restrict__ psums,
                                              float* __restrict__ rinv) {
  int i = blockIdx.x * 256 + threadIdx.x;       // 1024 total
  int n = i >> 6, k = i & 63;
  float s = 0.f;
  for (int tn = 0; tn < 64; tn++) s += psums[((size_t)n * 64 + tn) * 64 + k];
  rinv[i] = 1.0f / s;
}

// ---------- vlad partials: part[sk,n,k,d] = sum_l e[n,k,l] f[n,l,d] ----------
// e staged via gll16 of pre-swizzled images; XCD-grouped dt blocks.
__global__ __launch_bounds__(256) void k_vlad(const unsigned short* __restrict__ eg,
                                              const unsigned short* __restrict__ fT,
                                              float* __restrict__ part) {
  __shared__ __align__(16) char smem[49152];
  char* As = smem;            // 2 images x [64k x 128B]: byte = img*8192 + k*128 + ((l'*2)^((k&7)<<4))
  char* Bs = smem + 16384;    // [128d][128l]: byte = d*256 + ((l*2)^(((d&7)^((d>>3)&7))<<4))
  int t = threadIdx.x, lane = t & 63, wid = t >> 6;
  int wr = wid >> 1, wc = wid & 1;
  int lin = blockIdx.x;
  int xcd = lin & 7, jj = lin >> 3;
  int grp = xcd * 8 + (jj >> 2);                // 0..63 = (n,sk)
  int dt = jj & 3, n = grp >> 2, sk = grp & 3;
  int dbase = dt * 128;
  facc acc[2][4];
  facc zero = {0.f, 0.f, 0.f, 0.f};
  #pragma unroll
  for (int m = 0; m < 2; m++)
    #pragma unroll
    for (int j = 0; j < 4; j++) acc[m][j] = zero;

  for (int ks = 0; ks < 8; ks++) {
    int l0 = sk * 1024 + ks * 128;
    // stage A: two consecutive 8K e-images, contiguous 16K gll16
    {
      const char* easrc = (const char*)eg + ((size_t)n * 64 + (l0 >> 6)) * 8192;
      #pragma unroll
      for (int q = 0; q < 4; q++)
        gll16(easrc + (q * 4 + wid) * 1024 + lane * 16, As + (q * 4 + wid) * 1024);
    }
    // stage B transposed (fT rows l -> Bs[d][l]), swizzled scalar writes
    #pragma unroll
    for (int q = 0; q < 8; q++) {
      int ch = q * 256 + t;                      // l = ch>>4, dc = ch&15
      int l = ch >> 4, dc = ch & 15;
      bfrag v = *(const bfrag*)(fT + ((size_t)n * HW + l0 + l) * DD + dbase + dc * 8);
      #pragma unroll
      for (int i = 0; i < 8; i++) {
        int d = dc * 8 + i;
        int swz = (((d & 7) ^ ((d >> 3) & 7)) << 4);
        *(unsigned short*)(Bs + d * 256 + ((l * 2) ^ swz)) = (unsigned short)v[i];
      }
    }
    __syncthreads();
    #pragma unroll
    for (int kk = 0; kk < 128; kk += 32) {
      int lk = kk + ((lane >> 4) << 3);
      const char* Ai = As + (kk >> 6) * 8192;
      int ll = lk & 63;
      bfrag af[2], bf[4];
      #pragma unroll
      for (int m = 0; m < 2; m++) {
        int krow = wr * 32 + m * 16 + (lane & 15);
        af[m] = *(const bfrag*)(Ai + krow * 128 + ((ll * 2) ^ ((krow & 7) << 4)));
      }
      #pragma unroll
      for (int j = 0; j < 4; j++) {
        int d = wc * 64 + j * 16 + (lane & 15);
        int swz = (((d & 7) ^ ((d >> 3) & 7)) << 4);
        bf[j] = *(const bfrag*)(Bs + d * 256 + ((lk * 2) ^ swz));
      }
      #pragma unroll
      for (int m = 0; m < 2; m++)
        #pragma unroll
        for (int j = 0; j < 4; j++)
          acc[m][j] = __builtin_amdgcn_mfma_f32_16x16x32_bf16(af[m], bf[j], acc[m][j], 0, 0, 0);
    }
    __syncthreads();
  }
  int r0 = (lane >> 4) << 2, cl = lane & 15;
  size_t base = ((size_t)(sk * NB + n)) * (KC * DD);
  #pragma unroll
  for (int m = 0; m < 2; m++) {
    int krow = wr * 32 + m * 16 + r0;
    #pragma unroll
    for (int j = 0; j < 4; j++) {
      int d = dbase + wc * 64 + j * 16 + cl;
      #pragma unroll
      for (int q = 0; q < 4; q++)
        part[base + (size_t)(krow + q) * DD + d] = acc[m][j][q];
    }
  }
}

// ---------- reduce split-K partials (4) and normalize by rinv ----------
__global__ __launch_bounds__(256) void k_reduce(const float* __restrict__ part,
                                                const float* __restrict__ rinv,
                                                float* __restrict__ out) {
  int i = blockIdx.x * 256 + threadIdx.x;
  float s = 0.f;
  #pragma unroll
  for (int skk = 0; skk < 4; skk++) s += part[(size_t)skk * (NB * KC * DD) + i];
  out[i] = s * rinv[i >> 9];                    // i>>9 = n*64+k
}

extern "C" void kernel_launch(void* const* d_in, const int* in_sizes, int n_in,
                              void* d_out, int out_size, void* d_ws, size_t ws_size,
                              hipStream_t stream) {
  const float* x         = (const float*)d_in[0];
  const float* conv_w    = (const float*)d_in[1];
  const float* conv_b    = (const float*)d_in[2];
  const float* centroids = (const float*)d_in[3];
  float* out = (float*)d_out;
  char* ws = (char*)d_ws;

  // ws layout (bytes):
  //   Wsw   @ 0          (128 KB)   conv_w bf16, pre-swizzled 8x16K images
  //   Cbsw  @ 131072     (64 KB)    normalized centroids bf16, 8x8K images
  //   fT    @ 196608     (64 MB)    f bf16 (N,L,D)
  //   eg    @ 67305472   (8 MB)     exp(logits) bf16, N*64 x 8K images
  //   psums @ 75694080   (256 KB)   per-tile row sums fp32 (N,64,K)
  //   rinv  @ 75956224   (4 KB)     1/rowsum fp32 (N,K)
  //   part  @ 75960320   (8 MB)     vlad partials fp32 (4,N,K,D)
  unsigned short* Wsw  = (unsigned short*)(ws);
  unsigned short* Cbsw = (unsigned short*)(ws + 131072);
  unsigned short* fT   = (unsigned short*)(ws + 196608);
  unsigned short* eg   = (unsigned short*)(ws + 67305472ull);
  float*          psums= (float*)(ws + 75694080ull);
  float*          rinv = (float*)(ws + 75956224ull);
  float*          part = (float*)(ws + 75960320ull);

  k_prep<<<dim3(96), dim3(256), 0, stream>>>(conv_w, centroids, Wsw, Cbsw);

  // fused xnorm + projection + logits/exp -> fT, e-images, psums
  k_xproj<<<dim3(64, NB), dim3(512), 0, stream>>>(x, Wsw, Cbsw, conv_b, fT, eg, psums);

  k_rinv<<<dim3(4), dim3(256), 0, stream>>>(psums, rinv);

  // vlad partials: e(K,L) * f(L,D), split-L into 4 chunks of 1024
  k_vlad<<<dim3(256), dim3(256), 0, stream>>>(eg, fT, part);

  k_reduce<<<dim3(NB * KC * DD / 256), dim3(256), 0, stream>>>(part, rinv, out);

  (void)in_sizes; (void)n_in; (void)out_size; (void)ws_size;
}

// Round 10
// 69.305 us; speedup vs baseline: 1.0870x; 1.0870x over previous
//
#include <hip/hip_runtime.h>

#define NB 16     // batch
#define CD 128    // channels
#define HW 4096   // spatial L
#define DD 512    // projected dim
#define KC 64     // clusters

typedef __attribute__((ext_vector_type(8))) short bfrag;           // 8 bf16 (4 VGPR)
typedef __attribute__((ext_vector_type(4))) float facc;            // MFMA acc

__device__ __forceinline__ unsigned short f2bf(float f) {
  union { float f; unsigned u; } v; v.f = f;
  unsigned r = v.u + 0x7fffu + ((v.u >> 16) & 1u);   // RNE
  return (unsigned short)(r >> 16);
}
__device__ __forceinline__ float bf2f(unsigned short h) {
  union { unsigned u; float f; } v; v.u = ((unsigned)h) << 16; return v.f;
}
// packed f32x2 -> bf16x2 (RNE), low16 = lo
__device__ __forceinline__ unsigned f2bf2(float lo, float hi) {
  unsigned r;
  asm("v_cvt_pk_bf16_f32 %0, %1, %2" : "=v"(r) : "v"(lo), "v"(hi));
  return r;
}
// async global->LDS: HW writes lds_base + lane*16; global src carries per-lane offset
__device__ __forceinline__ void gll16(const void* g, void* l) {
  __builtin_amdgcn_global_load_lds(
      (__attribute__((address_space(1))) void*)(uintptr_t)g,
      (__attribute__((address_space(3))) void*)(uintptr_t)l, 16, 0, 0);
}
// row swizzle: 2-way-free on both b128 row-reads and strided writes
__device__ __forceinline__ int swzr(int r) { return ((r & 7) ^ ((r >> 3) & 7)) << 4; }

// ---------- prep: pre-swizzled W / normalized-centroid LDS images ----------
// Wsw:  4 images x [128d x 256B], byte = dch*32768 + d*256 + ((c*2)^swzr(d))
// Cbsw: 4 images x [64k x 256B],  byte = dch*16384 + k*256 + ((dl*2)^swzr(k))
__global__ __launch_bounds__(256) void k_prep(const float* __restrict__ conv_w,
                                              const float* __restrict__ centroids,
                                              unsigned short* __restrict__ Wsw,
                                              unsigned short* __restrict__ Cbsw) {
  int b = blockIdx.x, t = threadIdx.x;
  if (b < KC) {
    const float* row = centroids + (size_t)b * DD;
    float v0 = row[t], v1 = row[t + 256];
    float ss = v0 * v0 + v1 * v1;
    #pragma unroll
    for (int off = 32; off; off >>= 1) ss += __shfl_xor(ss, off);
    __shared__ float red[4];
    if ((t & 63) == 0) red[t >> 6] = ss;
    __syncthreads();
    float tot = red[0] + red[1] + red[2] + red[3];
    float inv = 1.0f / fmaxf(sqrtf(tot), 1e-12f);
    int d0 = t, d1 = t + 256;
    *(unsigned short*)((char*)Cbsw + (d0 >> 7) * 16384 + b * 256 +
                       (((d0 & 127) * 2) ^ swzr(b))) = f2bf(v0 * inv);
    *(unsigned short*)((char*)Cbsw + (d1 >> 7) * 16384 + b * 256 +
                       (((d1 & 127) * 2) ^ swzr(b))) = f2bf(v1 * inv);
  } else {
    int i = (b - KC) * 2048 + t * 8;            // 32 blocks cover 512x128
    const float4* src = (const float4*)(conv_w + i);
    float4 a = src[0], c4 = src[1];
    int d = i >> 7, c0 = i & 127;
    int dch = d >> 7, dl = d & 127;
    uint4 w;
    w.x = f2bf2(a.x, a.y);   w.y = f2bf2(a.z, a.w);
    w.z = f2bf2(c4.x, c4.y); w.w = f2bf2(c4.z, c4.w);
    *(uint4*)((char*)Wsw + dch * 32768 + dl * 256 + ((c0 * 2) ^ swzr(dl))) = w;
  }
}

// ---------- fused xnorm + projection + logits/exp (LDS-economy version) ----------
// Per block (n, 128 l): Xraw (l,c) once; inv[l] folded into f epilogue.
// 4 d-chunks of 128: f-MFMA (af hoisted, 2.0 MFMA/b128) -> fbuf -> fT dump + e-MFMA.
__global__ __launch_bounds__(512, 1) void k_xproj(const float* __restrict__ x,
                                                  const unsigned short* __restrict__ Wsw,
                                                  const unsigned short* __restrict__ Cbsw,
                                                  const float* __restrict__ conv_b,
                                                  unsigned short* __restrict__ fT,
                                                  unsigned short* __restrict__ eg,
                                                  float* __restrict__ psums) {
  __shared__ __align__(16) char smem[148992];
  char* Xraw = smem;                      // 128l x 256B: l*256 + ((c*2)^swzr(l))
  char* Ws   = smem + 32768;              // 128d x 256B (staged image)
  char* fbuf = smem + 65536;              // 128l x 256B: l*256 + ((d*2)^swzr(l))
  char* CbB[2] = { smem + 98304, smem + 114688 };  // 64k x 256B each
  char* etile = smem + 131072;            // 2 img x [64k x 128B]: k*128 + ((l''*2)^swzr(k))
  float* invb = (float*)(smem + 147456);  // [128]
  float* ps   = (float*)(smem + 147968);  // [64][4]
  int n = blockIdx.y, l0 = blockIdx.x * 128;
  int t = threadIdx.x, lane = t & 63, wid = t >> 6;

  // stage dch 0 (regions untouched by P1/P2)
  {
    #pragma unroll
    for (int q = 0; q < 4; q++)
      gll16((const char*)Wsw + (q * 8 + wid) * 1024 + lane * 16, Ws + (q * 8 + wid) * 1024);
    #pragma unroll
    for (int q = 0; q < 2; q++)
      gll16((const char*)Cbsw + (q * 8 + wid) * 1024 + lane * 16, CbB[0] + (q * 8 + wid) * 1024);
  }

  // P1: x fp32 (c-pair rows) -> bf16 -> Xraw (l,c), u32 pair-writes
  #pragma unroll
  for (int j = 0; j < 2; j++) {
    int c0 = ((t >> 4) + 32 * j) * 2;
    const float4* r0p = (const float4*)(x + ((size_t)n * CD + c0) * HW + l0);
    const float4* r1p = (const float4*)(x + ((size_t)n * CD + c0 + 1) * HW + l0);
    #pragma unroll
    for (int jj = 0; jj < 2; jj++) {
      int f4 = (t & 15) + 16 * jj;
      float4 a = r0p[f4], b = r1p[f4];
      int lb = f4 * 4;
      *(unsigned*)(Xraw + (lb + 0) * 256 + ((c0 * 2) ^ swzr(lb + 0))) = f2bf2(a.x, b.x);
      *(unsigned*)(Xraw + (lb + 1) * 256 + ((c0 * 2) ^ swzr(lb + 1))) = f2bf2(a.y, b.y);
      *(unsigned*)(Xraw + (lb + 2) * 256 + ((c0 * 2) ^ swzr(lb + 2))) = f2bf2(a.z, b.z);
      *(unsigned*)(Xraw + (lb + 3) * 256 + ((c0 * 2) ^ swzr(lb + 3))) = f2bf2(a.w, b.w);
    }
  }
  __syncthreads();                        // B1: Xraw ready; stage(0) drained

  // P2: inv[l] from row sums (b128 reads; XOR permutation is sum-invariant)
  {
    int l = t >> 2;
    float ss = 0.f;
    #pragma unroll
    for (int p = 0; p < 4; p++) {
      int s16 = (t & 3) + 4 * p;
      bfrag v = *(const bfrag*)(Xraw + l * 256 + ((s16 * 16) ^ swzr(l)));
      #pragma unroll
      for (int i = 0; i < 8; i++) { float f = bf2f((unsigned short)v[i]); ss += f * f; }
    }
    ss += __shfl_xor(ss, 1); ss += __shfl_xor(ss, 2);
    if ((t & 3) == 0) invb[l] = 1.0f / fmaxf(sqrtf(ss), 1e-12f);
  }
  __syncthreads();                        // B2: inv ready

  // hoists: af (A-fragments, dch-invariant) + inv per acc row
  int wr = wid >> 1, wc = wid & 1;        // f waves: 4(l) x 2(d)
  int er = wid >> 2, ec = wid & 3;        // e waves: 2(k) x 4(l)
  int r0 = (lane >> 4) << 2, cl = lane & 15;
  bfrag af[4][2];
  #pragma unroll
  for (int kk = 0; kk < 4; kk++)
    #pragma unroll
    for (int m = 0; m < 2; m++) {
      int row = wr * 32 + m * 16 + cl;
      int c0e = kk * 32 + ((lane >> 4) << 3);
      af[kk][m] = *(const bfrag*)(Xraw + row * 256 + ((c0e * 2) ^ swzr(row)));
    }
  float hinv[2][4];
  #pragma unroll
  for (int m = 0; m < 2; m++)
    #pragma unroll
    for (int q = 0; q < 4; q++) hinv[m][q] = invb[wr * 32 + m * 16 + r0 + q];

  facc zero = {0.f, 0.f, 0.f, 0.f};
  facc e_acc[2][2];
  e_acc[0][0] = zero; e_acc[0][1] = zero; e_acc[1][0] = zero; e_acc[1][1] = zero;

  #pragma unroll
  for (int dch = 0; dch < 4; dch++) {
    const char* Cbs = CbB[dch & 1];
    // f-MFMA: 128l x 128d, wave tile 32l x 64d (af in regs; 16 b128 -> 32 MFMA)
    facc acc[2][4];
    #pragma unroll
    for (int m = 0; m < 2; m++)
      #pragma unroll
      for (int j = 0; j < 4; j++) acc[m][j] = zero;
    #pragma unroll
    for (int kk = 0; kk < 4; kk++) {
      int c0e = kk * 32 + ((lane >> 4) << 3);
      bfrag bf[4];
      #pragma unroll
      for (int j = 0; j < 4; j++) {
        int d = wc * 64 + j * 16 + cl;
        bf[j] = *(const bfrag*)(Ws + d * 256 + ((c0e * 2) ^ swzr(d)));
      }
      #pragma unroll
      for (int m = 0; m < 2; m++)
        #pragma unroll
        for (int j = 0; j < 4; j++)
          acc[m][j] = __builtin_amdgcn_mfma_f32_16x16x32_bf16(af[kk][m], bf[j], acc[m][j], 0, 0, 0);
    }
    // epilogue: f = inv[l]*acc + bias -> fbuf (l,d)
    #pragma unroll
    for (int m = 0; m < 2; m++) {
      #pragma unroll
      for (int j = 0; j < 4; j++) {
        int d = wc * 64 + j * 16 + cl;
        float bv = conv_b[dch * 128 + d];
        #pragma unroll
        for (int q = 0; q < 4; q++) {
          int l = wr * 32 + m * 16 + r0 + q;
          *(unsigned short*)(fbuf + l * 256 + ((d * 2) ^ swzr(l))) =
              f2bf(acc[m][j][q] * hinv[m][q] + bv);
        }
      }
    }
    __syncthreads();                      // B_mid: fbuf ready; Ws reads done
    // issue next stage (lands by loop-top barrier; overlaps dump + e-MFMA)
    if (dch < 3) {
      #pragma unroll
      for (int q = 0; q < 4; q++)
        gll16((const char*)Wsw + (dch + 1) * 32768 + (q * 8 + wid) * 1024 + lane * 16,
              Ws + (q * 8 + wid) * 1024);
      #pragma unroll
      for (int q = 0; q < 2; q++)
        gll16((const char*)Cbsw + (dch + 1) * 16384 + (q * 8 + wid) * 1024 + lane * 16,
              CbB[(dch + 1) & 1] + (q * 8 + wid) * 1024);
    }
    // coalesced fT dump (stores overlap e-MFMA)
    {
      int l = t >> 2;
      #pragma unroll
      for (int p = 0; p < 4; p++) {
        int c16 = (t & 3) + 4 * p;
        bfrag v = *(const bfrag*)(fbuf + l * 256 + ((c16 * 16) ^ swzr(l)));
        *(bfrag*)(fT + ((size_t)n * HW + l0 + l) * DD + dch * 128 + c16 * 8) = v;
      }
    }
    // e-MFMA: e_acc += Cbs(64k x 128d) * fbuf(128l x 128d)^T, wave tile 32k x 32l
    #pragma unroll
    for (int kk = 0; kk < 4; kk++) {
      int d0 = kk * 32 + ((lane >> 4) << 3);
      bfrag ca[2], fb[2];
      #pragma unroll
      for (int m2 = 0; m2 < 2; m2++) {
        int k2 = er * 32 + m2 * 16 + cl;
        ca[m2] = *(const bfrag*)(Cbs + k2 * 256 + ((d0 * 2) ^ swzr(k2)));
      }
      #pragma unroll
      for (int j2 = 0; j2 < 2; j2++) {
        int l2 = ec * 32 + j2 * 16 + cl;
        fb[j2] = *(const bfrag*)(fbuf + l2 * 256 + ((d0 * 2) ^ swzr(l2)));
      }
      #pragma unroll
      for (int m2 = 0; m2 < 2; m2++)
        #pragma unroll
        for (int j2 = 0; j2 < 2; j2++)
          e_acc[m2][j2] = __builtin_amdgcn_mfma_f32_16x16x32_bf16(ca[m2], fb[j2], e_acc[m2][j2], 0, 0, 0);
    }
    __syncthreads();                      // B_top: stage drained; fbuf/Cbs reads done
  }

  // P5: exp -> etile + rowsum partials
  #pragma unroll
  for (int m2 = 0; m2 < 2; m2++) {
    #pragma unroll
    for (int q = 0; q < 4; q++) {
      int k2 = er * 32 + m2 * 16 + r0 + q;
      float vsum = 0.f;
      #pragma unroll
      for (int j2 = 0; j2 < 2; j2++) {
        int l2 = ec * 32 + j2 * 16 + cl;
        float ev = __expf(e_acc[m2][j2][q]);
        *(unsigned short*)(etile + (l2 >> 6) * 8192 + k2 * 128 +
                           (((l2 & 63) * 2) ^ swzr(k2))) = f2bf(ev);
        vsum += ev;
      }
      vsum += __shfl_xor(vsum, 1); vsum += __shfl_xor(vsum, 2);
      vsum += __shfl_xor(vsum, 4); vsum += __shfl_xor(vsum, 8);
      if (cl == 0) ps[k2 * 4 + ec] = vsum;
    }
  }
  __syncthreads();
  // dump 2 e-images (16 KB) + psums
  {
    size_t base = ((size_t)n * 64 + blockIdx.x * 2) * 8192;
    #pragma unroll
    for (int p = 0; p < 2; p++) {
      uint4 v = *(const uint4*)(etile + (t + p * 512) * 16);
      *(uint4*)((char*)eg + base + (t + p * 512) * 16) = v;
    }
  }
  if (t < 64) {
    float4 v = ((const float4*)ps)[t];
    psums[((size_t)n * 32 + blockIdx.x) * 64 + t] = v.x + v.y + v.z + v.w;
  }
}

// ---------- rinv[n,k] = 1 / sum_tiles psums ----------
__global__ __launch_bounds__(256) void k_rinv(const float* __restrict__ psums,
                                              float* __restrict__ rinv) {
  int i = blockIdx.x * 256 + threadIdx.x;       // 1024 total
  int n = i >> 6, k = i & 63;
  float s = 0.f;
  for (int tn = 0; tn < 32; tn++) s += psums[((size_t)n * 32 + tn) * 64 + k];
  rinv[i] = 1.0f / s;
}

// ---------- vlad partials: part[sk,n,k,d] = sum_l e[n,k,l] f[n,l,d] ----------
__global__ __launch_bounds__(256) void k_vlad(const unsigned short* __restrict__ eg,
                                              const unsigned short* __restrict__ fT,
                                              float* __restrict__ part) {
  __shared__ __align__(16) char smem[49152];
  char* As = smem;            // 2 images x [64k x 128B]: k*128 + ((l''*2)^swzr(k))
  char* Bs = smem + 16384;    // [128d][128l]: d*256 + ((l*2)^(((d&7)^((d>>3)&7))<<4))
  int t = threadIdx.x, lane = t & 63, wid = t >> 6;
  int wr = wid >> 1, wc = wid & 1;
  int lin = blockIdx.x;
  int xcd = lin & 7, jj = lin >> 3;
  int grp = xcd * 8 + (jj >> 2);                // 0..63 = (n,sk)
  int dt = jj & 3, n = grp >> 2, sk = grp & 3;
  int dbase = dt * 128;
  facc acc[2][4];
  facc zero = {0.f, 0.f, 0.f, 0.f};
  #pragma unroll
  for (int m = 0; m < 2; m++)
    #pragma unroll
    for (int j = 0; j < 4; j++) acc[m][j] = zero;

  for (int ks = 0; ks < 8; ks++) {
    int l0 = sk * 1024 + ks * 128;
    {   // stage A: two consecutive 8K e-images via gll16
      const char* easrc = (const char*)eg + ((size_t)n * 64 + (l0 >> 6)) * 8192;
      #pragma unroll
      for (int q = 0; q < 4; q++)
        gll16(easrc + (q * 4 + wid) * 1024 + lane * 16, As + (q * 4 + wid) * 1024);
    }
    // stage B transposed (fT rows l -> Bs[d][l])
    #pragma unroll
    for (int q = 0; q < 8; q++) {
      int ch = q * 256 + t;
      int l = ch >> 4, dc = ch & 15;
      bfrag v = *(const bfrag*)(fT + ((size_t)n * HW + l0 + l) * DD + dbase + dc * 8);
      #pragma unroll
      for (int i = 0; i < 8; i++) {
        int d = dc * 8 + i;
        int swz = (((d & 7) ^ ((d >> 3) & 7)) << 4);
        *(unsigned short*)(Bs + d * 256 + ((l * 2) ^ swz)) = (unsigned short)v[i];
      }
    }
    __syncthreads();
    #pragma unroll
    for (int kk = 0; kk < 128; kk += 32) {
      int lk = kk + ((lane >> 4) << 3);
      const char* Ai = As + (kk >> 6) * 8192;
      int ll = lk & 63;
      bfrag af[2], bf[4];
      #pragma unroll
      for (int m = 0; m < 2; m++) {
        int krow = wr * 32 + m * 16 + (lane & 15);
        af[m] = *(const bfrag*)(Ai + krow * 128 + ((ll * 2) ^ swzr(krow)));
      }
      #pragma unroll
      for (int j = 0; j < 4; j++) {
        int d = wc * 64 + j * 16 + (lane & 15);
        int swz = (((d & 7) ^ ((d >> 3) & 7)) << 4);
        bf[j] = *(const bfrag*)(Bs + d * 256 + ((lk * 2) ^ swz));
      }
      #pragma unroll
      for (int m = 0; m < 2; m++)
        #pragma unroll
        for (int j = 0; j < 4; j++)
          acc[m][j] = __builtin_amdgcn_mfma_f32_16x16x32_bf16(af[m], bf[j], acc[m][j], 0, 0, 0);
    }
    __syncthreads();
  }
  int r0 = (lane >> 4) << 2, cl = lane & 15;
  size_t base = ((size_t)(sk * NB + n)) * (KC * DD);
  #pragma unroll
  for (int m = 0; m < 2; m++) {
    int krow = wr * 32 + m * 16 + r0;
    #pragma unroll
    for (int j = 0; j < 4; j++) {
      int d = dbase + wc * 64 + j * 16 + cl;
      #pragma unroll
      for (int q = 0; q < 4; q++)
        part[base + (size_t)(krow + q) * DD + d] = acc[m][j][q];
    }
  }
}

// ---------- reduce split-K partials (4) and normalize by rinv ----------
__global__ __launch_bounds__(256) void k_reduce(const float* __restrict__ part,
                                                const float* __restrict__ rinv,
                                                float* __restrict__ out) {
  int i = blockIdx.x * 256 + threadIdx.x;
  float s = 0.f;
  #pragma unroll
  for (int skk = 0; skk < 4; skk++) s += part[(size_t)skk * (NB * KC * DD) + i];
  out[i] = s * rinv[i >> 9];                    // i>>9 = n*64+k
}

extern "C" void kernel_launch(void* const* d_in, const int* in_sizes, int n_in,
                              void* d_out, int out_size, void* d_ws, size_t ws_size,
                              hipStream_t stream) {
  const float* x         = (const float*)d_in[0];
  const float* conv_w    = (const float*)d_in[1];
  const float* conv_b    = (const float*)d_in[2];
  const float* centroids = (const float*)d_in[3];
  float* out = (float*)d_out;
  char* ws = (char*)d_ws;

  // ws layout (bytes):
  //   Wsw   @ 0          (128 KB)   conv_w bf16, 4x32K pre-swizzled images
  //   Cbsw  @ 131072     (64 KB)    normalized centroids bf16, 4x16K images
  //   fT    @ 196608     (64 MB)    f bf16 (N,L,D)
  //   eg    @ 67305472   (8 MB)     exp(logits) bf16, N*64 x 8K images
  //   psums @ 75694080   (128 KB)   per-tile row sums fp32 (N,32,K)
  //   rinv  @ 75956224   (4 KB)     1/rowsum fp32 (N,K)
  //   part  @ 75960320   (8 MB)     vlad partials fp32 (4,N,K,D)
  unsigned short* Wsw  = (unsigned short*)(ws);
  unsigned short* Cbsw = (unsigned short*)(ws + 131072);
  unsigned short* fT   = (unsigned short*)(ws + 196608);
  unsigned short* eg   = (unsigned short*)(ws + 67305472ull);
  float*          psums= (float*)(ws + 75694080ull);
  float*          rinv = (float*)(ws + 75956224ull);
  float*          part = (float*)(ws + 75960320ull);

  k_prep<<<dim3(96), dim3(256), 0, stream>>>(conv_w, centroids, Wsw, Cbsw);

  // fused xnorm + projection + logits/exp -> fT, e-images, psums
  k_xproj<<<dim3(32, NB), dim3(512), 0, stream>>>(x, Wsw, Cbsw, conv_b, fT, eg, psums);

  k_rinv<<<dim3(4), dim3(256), 0, stream>>>(psums, rinv);

  // vlad partials: e(K,L) * f(L,D), split-L into 4 chunks of 1024
  k_vlad<<<dim3(256), dim3(256), 0, stream>>>(eg, fT, part);

  k_reduce<<<dim3(NB * KC * DD / 256), dim3(256), 0, stream>>>(part, rinv, out);

  (void)in_sizes; (void)n_in; (void)out_size; (void)ws_size;
}